// Round 1
// baseline (141.264 us; speedup 1.0000x reference)
//
#include <hip/hip_runtime.h>
#include <hip/hip_bf16.h>

typedef float f32x4 __attribute__((ext_vector_type(4)));
typedef __bf16 bf16x8 __attribute__((ext_vector_type(8)));

#define EPSF 1e-5f

// ---------------------------------------------------------------- pooling ---
// P[n][c][l], l<128: sum_w pw(w)*x[n][c][l][w]; l>=128: sum_h pw(h)*x[n][c][h][l-128]
__device__ __forceinline__ float pw(int i) {
    return (1.0f + (i < 64 ? 2.0f : 0.0f) + (i < 32 ? 4.0f : 0.0f)) * (1.0f / 128.0f);
}

__global__ __launch_bounds__(256) void pool_kernel(const float* __restrict__ x,
                                                   float* __restrict__ P) {
    int nc = blockIdx.x;  // n*128 + c
    const f32x4* plane = (const f32x4*)(x + (size_t)nc * 16384);
    __shared__ float rowpart[128][33];
    __shared__ __align__(16) f32x4 colpart[8][32];
    int t = threadIdx.x;
    int wq = t & 31, hg = t >> 5;
    f32x4 cacc = {0.f, 0.f, 0.f, 0.f};
    float u0 = pw(wq * 4), u1 = pw(wq * 4 + 1), u2 = pw(wq * 4 + 2), u3 = pw(wq * 4 + 3);
    #pragma unroll
    for (int j = 0; j < 16; ++j) {
        int r = hg * 16 + j;
        f32x4 v = plane[r * 32 + wq];
        rowpart[r][wq] = v.x * u0 + v.y * u1 + v.z * u2 + v.w * u3;
        cacc += v * pw(r);
    }
    colpart[hg][wq] = cacc;
    __syncthreads();
    float s = 0.f;
    if (t < 128) {
        #pragma unroll
        for (int q = 0; q < 32; ++q) s += rowpart[t][q];
        P[(size_t)nc * 256 + t] = s;
    } else {
        int w = t - 128;
        const float* cp = (const float*)colpart;
        #pragma unroll
        for (int g = 0; g < 8; ++g) s += cp[g * 128 + w];
        P[(size_t)nc * 256 + 128 + w] = s;
    }
}

// ---------------------------------------------------- attention vectors -----
// A2[n][c][l]: l<128 -> a_h[n][c][h=l]; l>=128 -> a_w[n][c][w=l-128]
__global__ __launch_bounds__(256) void attn_kernel(const float* __restrict__ P,
    const float* __restrict__ w1, const float* __restrict__ b1,
    const float* __restrict__ g1, const float* __restrict__ be1,
    const float* __restrict__ m1, const float* __restrict__ v1,
    const float* __restrict__ wh, const float* __restrict__ bh,
    const float* __restrict__ ww, const float* __restrict__ bw,
    float* __restrict__ A2) {
    int n = blockIdx.x, t = threadIdx.x;
    __shared__ float w1s[1024], whs[1024], wws[1024];
    __shared__ float bhs[128], bws[128];
    __shared__ float s1[8], t1[8], b1s[8];
    for (int i = t; i < 1024; i += 256) { w1s[i] = w1[i]; whs[i] = wh[i]; wws[i] = ww[i]; }
    if (t < 128) { bhs[t] = bh[t]; bws[t] = bw[t]; }
    if (t < 8) {
        float s = g1[t] * rsqrtf(v1[t] + EPSF);
        s1[t] = s; t1[t] = be1[t] - m1[t] * s; b1s[t] = b1[t];
    }
    __syncthreads();
    float y[8];
    #pragma unroll
    for (int m = 0; m < 8; ++m) y[m] = b1s[m];
    const float* Pn = P + (size_t)n * 32768;
    for (int c = 0; c < 128; ++c) {
        float pv = Pn[c * 256 + t];
        #pragma unroll
        for (int m = 0; m < 8; ++m) y[m] += w1s[m * 128 + c] * pv;
    }
    #pragma unroll
    for (int m = 0; m < 8; ++m) {
        float v = y[m] * s1[m] + t1[m];                    // bn
        float cl = fminf(fmaxf(v + 3.f, 0.f), 6.f);        // h_swish
        y[m] = v * cl * (1.f / 6.f);
    }
    const float* Ws = (t < 128) ? whs : wws;   // wave-uniform
    const float* Bs = (t < 128) ? bhs : bws;
    float* On = A2 + (size_t)n * 32768;
    for (int c = 0; c < 128; ++c) {
        float a = Bs[c];
        #pragma unroll
        for (int m = 0; m < 8; ++m) a += y[m] * Ws[c * 8 + m];
        On[c * 256 + t] = 1.f / (1.f + __expf(-a));
    }
}

// -------------------------------------------- weight transform + BN consts --
// Wt[khw][o][c] = wc[o][c][kh][kw] in bf16;  ab[o]=scale, ab[128+o]=offset
__global__ __launch_bounds__(256) void wtrans_kernel(const float* __restrict__ wc,
    const float* __restrict__ bc, const float* __restrict__ g2, const float* __restrict__ be2,
    const float* __restrict__ m2, const float* __restrict__ v2,
    __hip_bfloat16* __restrict__ Wt, float* __restrict__ ab) {
    int g = blockIdx.x * 256 + threadIdx.x;   // 576*256 == 147456 exactly
    int khw = g >> 14, rem = g & 16383, o = rem >> 7, c = rem & 127;
    Wt[g] = __float2bfloat16(wc[(o * 128 + c) * 9 + khw]);
    if (g < 128) {
        float s2 = g2[g] * rsqrtf(v2[g] + EPSF);
        ab[g] = s2;
        ab[128 + g] = bc[g] * s2 + be2[g] - m2[g] * s2;
    }
}

// ------------------------------------------------------------ zero borders --
__global__ __launch_bounds__(256) void border_kernel(__hip_bfloat16* __restrict__ Xpad) {
    int g = blockIdx.x * 256 + threadIdx.x;   // 66048 uint4 writes
    if (g >= 66048) return;
    int pi = g >> 4, cb = g & 15;
    int n = pi / 516, b = pi - n * 516;
    int hp, wp;
    if (b < 130)      { hp = 0;   wp = b; }
    else if (b < 260) { hp = 129; wp = b - 130; }
    else if (b < 388) { wp = 0;   hp = b - 259; }
    else              { wp = 129; hp = b - 387; }
    uint4 z = {0u, 0u, 0u, 0u};
    *(uint4*)(Xpad + (size_t)(n * 16900 + hp * 130 + wp) * 128 + cb * 8) = z;
}

// ------------------------------------------- attention multiply -> NHWC bf16
__device__ __forceinline__ int ldsoff(int w, int c) {
    // [w][c] tile, 16B-slot XOR swizzle so both b16 writes and b128 reads balance banks
    return w * 128 + ((((c >> 3) ^ ((w & 7) << 1)) << 3) | (c & 7));
}

__global__ __launch_bounds__(256) void amul_kernel(const float* __restrict__ x,
    const float* __restrict__ A2, __hip_bfloat16* __restrict__ Xpad) {
    int nh = blockIdx.x;             // n*128 + h
    int n = nh >> 7, h = nh & 127;
    int t = threadIdx.x;
    __shared__ __align__(16) __hip_bfloat16 T[16384];
    __shared__ float ahs[128];
    if (t < 128) ahs[t] = A2[(size_t)(n * 128 + t) * 256 + h];
    __syncthreads();
    const float* xr  = x + ((size_t)n * 128 * 128 + h) * 128;
    const float* awr = A2 + (size_t)n * 32768 + 128;
    #pragma unroll
    for (int j = 0; j < 16; ++j) {
        int item = j * 256 + t;
        int c = item >> 5, w4 = item & 31;
        f32x4 xv = *(const f32x4*)(xr + (size_t)c * 16384 + w4 * 4);
        f32x4 av = *(const f32x4*)(awr + c * 256 + w4 * 4);
        float ah = ahs[c];
        #pragma unroll
        for (int k = 0; k < 4; ++k) {
            float val = xv[k] * av[k] * ah;
            T[ldsoff(w4 * 4 + k, c)] = __float2bfloat16(val);
        }
    }
    __syncthreads();
    __hip_bfloat16* orow = Xpad + (size_t)(n * 16900 + (h + 1) * 130 + 1) * 128;
    #pragma unroll
    for (int j = 0; j < 8; ++j) {
        int item = j * 256 + t;
        int w = item >> 4, cb = item & 15;
        int slot = cb ^ ((w & 7) << 1);
        uint4 v = *(const uint4*)&T[w * 128 + slot * 8];
        *(uint4*)(orow + w * 128 + cb * 8) = v;
    }
}

// ------------------------------------------------------- implicit-GEMM conv -
// Block: one (n,h) row: 128 spatial x 128 outch. K = 9*128, BK=32.
// M = outch (so stores are w-contiguous), N = spatial.
__global__ __launch_bounds__(256) void conv_kernel(
    const __hip_bfloat16* __restrict__ Xpad, const __hip_bfloat16* __restrict__ Wt,
    const float* __restrict__ ab, float* __restrict__ out) {
    int bid = blockIdx.x;
    int work = (bid & 7) * 128 + (bid >> 3);   // XCD swizzle: one image per XCD
    int n = work >> 7, h = work & 127;
    int tid = threadIdx.x, lane = tid & 63, wid = tid >> 6;
    int wo = wid >> 1, wp = wid & 1;

    __shared__ __align__(16) __hip_bfloat16 Xl[2][4096];   // [p=128][k=32]
    __shared__ __align__(16) __hip_bfloat16 Wl[2][4096];   // [o=128][k=32]

    const __hip_bfloat16* Xn = Xpad + (size_t)n * (16900 * 128);

    f32x4 acc[4][4];
    #pragma unroll
    for (int i = 0; i < 4; ++i)
        #pragma unroll
        for (int j = 0; j < 4; ++j) acc[i][j] = (f32x4){0.f, 0.f, 0.f, 0.f};

    auto stage = [&](int kk, int buf) {
        int khw = kk >> 2, cc = (kk & 3) << 5;
        int kh = khw / 3, kw = khw - kh * 3;
        const __hip_bfloat16* xb = Xn + (size_t)((h + kh) * 130 + kw) * 128 + cc;
        const __hip_bfloat16* wb = Wt + khw * 16384 + cc;
        #pragma unroll
        for (int j = 0; j < 2; ++j) {
            int idx = j * 256 + tid;
            int p = idx >> 2, s = idx & 3;
            const __hip_bfloat16* src = xb + p * 128 + 8 * (s ^ ((p >> 1) & 3));
            __builtin_amdgcn_global_load_lds(
                (const __attribute__((address_space(1))) void*)src,
                (__attribute__((address_space(3))) void*)(&Xl[buf][idx * 8]), 16, 0, 0);
        }
        #pragma unroll
        for (int j = 0; j < 2; ++j) {
            int idx = j * 256 + tid;
            int o = idx >> 2, s = idx & 3;
            const __hip_bfloat16* src = wb + o * 128 + 8 * (s ^ ((o >> 1) & 3));
            __builtin_amdgcn_global_load_lds(
                (const __attribute__((address_space(1))) void*)src,
                (__attribute__((address_space(3))) void*)(&Wl[buf][idx * 8]), 16, 0, 0);
        }
    };

    stage(0, 0);
    __syncthreads();

    int u = lane >> 4, r16 = lane & 15;
    for (int kk = 0; kk < 36; ++kk) {
        int buf = kk & 1;
        if (kk < 35) stage(kk + 1, buf ^ 1);
        bf16x8 wf[4], xf[4];
        #pragma unroll
        for (int mi = 0; mi < 4; ++mi) {
            int o = wo * 64 + mi * 16 + r16;
            wf[mi] = *(const bf16x8*)&Wl[buf][o * 32 + 8 * (u ^ ((o >> 1) & 3))];
        }
        #pragma unroll
        for (int ni = 0; ni < 4; ++ni) {
            int p = wp * 64 + ni * 16 + r16;
            xf[ni] = *(const bf16x8*)&Xl[buf][p * 32 + 8 * (u ^ ((p >> 1) & 3))];
        }
        #pragma unroll
        for (int mi = 0; mi < 4; ++mi)
            #pragma unroll
            for (int ni = 0; ni < 4; ++ni)
                acc[mi][ni] = __builtin_amdgcn_mfma_f32_16x16x32_bf16(
                    wf[mi], xf[ni], acc[mi][ni], 0, 0, 0);
        __syncthreads();
    }

    // fused bias + BN + SiLU epilogue
    #pragma unroll
    for (int mi = 0; mi < 4; ++mi) {
        #pragma unroll
        for (int r = 0; r < 4; ++r) {
            int o = wo * 64 + mi * 16 + u * 4 + r;
            float al = ab[o], be = ab[128 + o];
            size_t obase = (((size_t)n * 128 + o) * 128 + h) * 128;
            #pragma unroll
            for (int ni = 0; ni < 4; ++ni) {
                int p = wp * 64 + ni * 16 + r16;
                float z = acc[mi][ni][r] * al + be;
                out[obase + p] = z / (1.f + __expf(-z));
            }
        }
    }
}

// ----------------------------------------------------------------- launch ---
extern "C" void kernel_launch(void* const* d_in, const int* in_sizes, int n_in,
                              void* d_out, int out_size, void* d_ws, size_t ws_size,
                              hipStream_t stream) {
    const float* x   = (const float*)d_in[0];
    const float* w1  = (const float*)d_in[1];
    const float* b1  = (const float*)d_in[2];
    const float* g1  = (const float*)d_in[3];
    const float* be1 = (const float*)d_in[4];
    const float* m1  = (const float*)d_in[5];
    const float* v1  = (const float*)d_in[6];
    const float* wh  = (const float*)d_in[7];
    const float* bh  = (const float*)d_in[8];
    const float* ww  = (const float*)d_in[9];
    const float* bw  = (const float*)d_in[10];
    const float* wc  = (const float*)d_in[11];
    const float* bc  = (const float*)d_in[12];
    const float* g2  = (const float*)d_in[13];
    const float* be2 = (const float*)d_in[14];
    const float* m2  = (const float*)d_in[15];
    const float* v2  = (const float*)d_in[16];
    float* out = (float*)d_out;

    // workspace layout (needs ~35.3 MiB)
    char* ws = (char*)d_ws;
    float* P  = (float*)(ws);                                   // 1 MiB
    float* A2 = (float*)(ws + (1 << 20));                       // 1 MiB
    __hip_bfloat16* Xpad = (__hip_bfloat16*)(ws + (2 << 20));   // 8*130*130*128*2 = 34,611,200
    __hip_bfloat16* Wt   = (__hip_bfloat16*)(ws + (2 << 20) + 34611200);  // 294,912
    float* ab = (float*)(ws + (2 << 20) + 34611200 + 294912);   // 1 KiB

    pool_kernel<<<1024, 256, 0, stream>>>(x, P);
    attn_kernel<<<8, 256, 0, stream>>>(P, w1, b1, g1, be1, m1, v1, wh, bh, ww, bw, A2);
    wtrans_kernel<<<576, 256, 0, stream>>>(wc, bc, g2, be2, m2, v2, Wt, ab);
    border_kernel<<<258, 256, 0, stream>>>(Xpad);
    amul_kernel<<<1024, 256, 0, stream>>>(x, A2, Xpad);
    conv_kernel<<<1024, 256, 0, stream>>>(Xpad, Wt, ab, out);
}

// Round 2
// 126.403 us; speedup vs baseline: 1.1176x; 1.1176x over previous
//
#include <hip/hip_runtime.h>
#include <hip/hip_bf16.h>

typedef float f32x4 __attribute__((ext_vector_type(4)));
typedef __bf16 bf16x8 __attribute__((ext_vector_type(8)));

#define EPSF 1e-5f

// ---------------------------------------------------------------- pooling ---
__device__ __forceinline__ float pw(int i) {
    return (1.0f + (i < 64 ? 2.0f : 0.0f) + (i < 32 ? 4.0f : 0.0f)) * (1.0f / 128.0f);
}

__global__ __launch_bounds__(256) void pool_kernel(const float* __restrict__ x,
                                                   float* __restrict__ P) {
    int nc = blockIdx.x;  // n*128 + c
    const f32x4* plane = (const f32x4*)(x + (size_t)nc * 16384);
    __shared__ float rowpart[128][33];
    __shared__ __align__(16) f32x4 colpart[8][32];
    int t = threadIdx.x;
    int wq = t & 31, hg = t >> 5;
    f32x4 cacc = {0.f, 0.f, 0.f, 0.f};
    float u0 = pw(wq * 4), u1 = pw(wq * 4 + 1), u2 = pw(wq * 4 + 2), u3 = pw(wq * 4 + 3);
    #pragma unroll
    for (int j = 0; j < 16; ++j) {
        int r = hg * 16 + j;
        f32x4 v = plane[r * 32 + wq];
        rowpart[r][wq] = v.x * u0 + v.y * u1 + v.z * u2 + v.w * u3;
        cacc += v * pw(r);
    }
    colpart[hg][wq] = cacc;
    __syncthreads();
    float s = 0.f;
    if (t < 128) {
        #pragma unroll
        for (int q = 0; q < 32; ++q) s += rowpart[t][q];
        P[(size_t)nc * 256 + t] = s;
    } else {
        int w = t - 128;
        const float* cp = (const float*)colpart;
        #pragma unroll
        for (int g = 0; g < 8; ++g) s += cp[g * 128 + w];
        P[(size_t)nc * 256 + 128 + w] = s;
    }
}

// ---------------------------------------------------- attention vectors -----
__global__ __launch_bounds__(256) void attn_kernel(const float* __restrict__ P,
    const float* __restrict__ w1, const float* __restrict__ b1,
    const float* __restrict__ g1, const float* __restrict__ be1,
    const float* __restrict__ m1, const float* __restrict__ v1,
    const float* __restrict__ wh, const float* __restrict__ bh,
    const float* __restrict__ ww, const float* __restrict__ bw,
    float* __restrict__ A2) {
    int n = blockIdx.x, t = threadIdx.x;
    __shared__ float w1s[1024], whs[1024], wws[1024];
    __shared__ float bhs[128], bws[128];
    __shared__ float s1[8], t1[8], b1s[8];
    for (int i = t; i < 1024; i += 256) { w1s[i] = w1[i]; whs[i] = wh[i]; wws[i] = ww[i]; }
    if (t < 128) { bhs[t] = bh[t]; bws[t] = bw[t]; }
    if (t < 8) {
        float s = g1[t] * rsqrtf(v1[t] + EPSF);
        s1[t] = s; t1[t] = be1[t] - m1[t] * s; b1s[t] = b1[t];
    }
    __syncthreads();
    float y[8];
    #pragma unroll
    for (int m = 0; m < 8; ++m) y[m] = b1s[m];
    const float* Pn = P + (size_t)n * 32768;
    for (int c = 0; c < 128; ++c) {
        float pv = Pn[c * 256 + t];
        #pragma unroll
        for (int m = 0; m < 8; ++m) y[m] += w1s[m * 128 + c] * pv;
    }
    #pragma unroll
    for (int m = 0; m < 8; ++m) {
        float v = y[m] * s1[m] + t1[m];
        float cl = fminf(fmaxf(v + 3.f, 0.f), 6.f);
        y[m] = v * cl * (1.f / 6.f);
    }
    const float* Ws = (t < 128) ? whs : wws;   // wave-uniform
    const float* Bs = (t < 128) ? bhs : bws;
    float* On = A2 + (size_t)n * 32768;
    for (int c = 0; c < 128; ++c) {
        float a = Bs[c];
        #pragma unroll
        for (int m = 0; m < 8; ++m) a += y[m] * Ws[c * 8 + m];
        On[c * 256 + t] = 1.f / (1.f + __expf(-a));
    }
}

// -------------------------------------------- weight transform + BN consts --
__global__ __launch_bounds__(256) void wtrans_kernel(const float* __restrict__ wc,
    const float* __restrict__ bc, const float* __restrict__ g2, const float* __restrict__ be2,
    const float* __restrict__ m2, const float* __restrict__ v2,
    __hip_bfloat16* __restrict__ Wt, float* __restrict__ ab) {
    int g = blockIdx.x * 256 + threadIdx.x;   // 576*256 == 147456 exactly
    int khw = g >> 14, rem = g & 16383, o = rem >> 7, c = rem & 127;
    Wt[g] = __float2bfloat16(wc[(o * 128 + c) * 9 + khw]);
    if (g < 128) {
        float s2 = g2[g] * rsqrtf(v2[g] + EPSF);
        ab[g] = s2;
        ab[128 + g] = bc[g] * s2 + be2[g] - m2[g] * s2;
    }
}

// ------------------------------------------------------------ zero borders --
__global__ __launch_bounds__(256) void border_kernel(__hip_bfloat16* __restrict__ Xpad) {
    int g = blockIdx.x * 256 + threadIdx.x;   // 66048 uint4 writes
    if (g >= 66048) return;
    int pi = g >> 4, cb = g & 15;
    int n = pi / 516, b = pi - n * 516;
    int hp, wp;
    if (b < 130)      { hp = 0;   wp = b; }
    else if (b < 260) { hp = 129; wp = b - 130; }
    else if (b < 388) { wp = 0;   hp = b - 259; }
    else              { wp = 129; hp = b - 387; }
    uint4 z = {0u, 0u, 0u, 0u};
    *(uint4*)(Xpad + (size_t)(n * 16900 + hp * 130 + wp) * 128 + cb * 8) = z;
}

// ------------------------------------------- attention multiply -> NHWC bf16
__device__ __forceinline__ int ldsoff(int w, int c) {
    return w * 128 + ((((c >> 3) ^ ((w & 7) << 1)) << 3) | (c & 7));
}

__global__ __launch_bounds__(256) void amul_kernel(const float* __restrict__ x,
    const float* __restrict__ A2, __hip_bfloat16* __restrict__ Xpad) {
    int nh = blockIdx.x;             // n*128 + h
    int n = nh >> 7, h = nh & 127;
    int t = threadIdx.x;
    __shared__ __align__(16) __hip_bfloat16 T[16384];
    __shared__ float ahs[128];
    if (t < 128) ahs[t] = A2[(size_t)(n * 128 + t) * 256 + h];
    __syncthreads();
    const float* xr  = x + ((size_t)n * 128 * 128 + h) * 128;
    const float* awr = A2 + (size_t)n * 32768 + 128;
    #pragma unroll
    for (int j = 0; j < 16; ++j) {
        int item = j * 256 + t;
        int c = item >> 5, w4 = item & 31;
        f32x4 xv = *(const f32x4*)(xr + (size_t)c * 16384 + w4 * 4);
        f32x4 av = *(const f32x4*)(awr + c * 256 + w4 * 4);
        float ah = ahs[c];
        #pragma unroll
        for (int k = 0; k < 4; ++k) {
            float val = xv[k] * av[k] * ah;
            T[ldsoff(w4 * 4 + k, c)] = __float2bfloat16(val);
        }
    }
    __syncthreads();
    __hip_bfloat16* orow = Xpad + (size_t)(n * 16900 + (h + 1) * 130 + 1) * 128;
    #pragma unroll
    for (int j = 0; j < 8; ++j) {
        int item = j * 256 + t;
        int w = item >> 4, cb = item & 15;
        int slot = cb ^ ((w & 7) << 1);
        uint4 v = *(const uint4*)&T[w * 128 + slot * 8];
        *(uint4*)(orow + w * 128 + cb * 8) = v;
    }
}

// ------------------------------------------------------- implicit-GEMM conv -
// 512 threads (8 waves, 2Mx4N), tile M=128 (outch) x N=256 (2 output rows),
// BK=64, triple-buffered LDS, 4 phases/K-step, counted vmcnt (never 0 in loop).
__global__ __launch_bounds__(512, 2) void conv_kernel(
    const __hip_bfloat16* __restrict__ Xpad, const __hip_bfloat16* __restrict__ Wt,
    const float* __restrict__ ab, float* __restrict__ out) {
    int bid = blockIdx.x;
    int work = (bid & 7) * 64 + (bid >> 3);   // XCD swizzle, 512 % 8 == 0
    int n = work >> 6, h0 = (work & 63) * 2;
    int tid = threadIdx.x;
    int lane = tid & 63, wid = tid >> 6;
    int wm = wid >> 2, wn = wid & 3;
    int r16 = lane & 15, u = lane >> 4;

    __shared__ __hip_bfloat16 Wl[3 * 8192];    // [buf][o=128][k=64]
    __shared__ __hip_bfloat16 Xl[3 * 16384];   // [buf][p=256][k=64]

    const __hip_bfloat16* Xb = Xpad + (size_t)n * (16900 * 128) + h0 * 130 * 128;

    // per-thread staging source offsets (elements), swizzle-inverted on source
    int woff[2], xoff[4];
    #pragma unroll
    for (int j = 0; j < 2; ++j) {
        int idx = j * 512 + tid, o = idx >> 3, s = idx & 7;
        woff[j] = o * 128 + ((s ^ (o & 7)) << 3);
    }
    #pragma unroll
    for (int j = 0; j < 4; ++j) {
        int idx = j * 512 + tid, r = idx >> 3, s = idx & 7;
        int r2 = r >> 7, w = r & 127;
        xoff[j] = (r2 * 130 + w) * 128 + ((s ^ (r & 7)) << 3);
    }
    // fragment ds_read offsets (swizzled)
    int swz[2];
    swz[0] = ((0 + u) ^ (r16 & 7)) << 3;
    swz[1] = ((4 + u) ^ (r16 & 7)) << 3;
    int offA[4][2], offB[4][2];
    #pragma unroll
    for (int i = 0; i < 4; ++i) {
        int o = wm * 64 + i * 16 + r16;
        int p = wn * 64 + i * 16 + r16;
        #pragma unroll
        for (int k2 = 0; k2 < 2; ++k2) {
            offA[i][k2] = o * 64 + swz[k2];
            offB[i][k2] = p * 64 + swz[k2];
        }
    }

    auto stageW = [&](int t) {
        int khw = t >> 1, ch = t & 1;
        const __hip_bfloat16* src = Wt + khw * 16384 + ch * 64;
        __hip_bfloat16* dst = &Wl[(t % 3) * 8192];
        #pragma unroll
        for (int j = 0; j < 2; ++j)
            __builtin_amdgcn_global_load_lds(
                (const __attribute__((address_space(1))) void*)(src + woff[j]),
                (__attribute__((address_space(3))) void*)(dst + (j * 512 + tid) * 8), 16, 0, 0);
    };
    auto stageX = [&](int t, int jlo) {
        int khw = t >> 1, ch = t & 1;
        int kh = (khw * 11) >> 5, kw = khw - kh * 3;
        const __hip_bfloat16* src = Xb + (kh * 130 + kw) * 128 + ch * 64;
        __hip_bfloat16* dst = &Xl[(t % 3) * 16384];
        #pragma unroll
        for (int j = jlo; j < jlo + 2; ++j)
            __builtin_amdgcn_global_load_lds(
                (const __attribute__((address_space(1))) void*)(src + xoff[j]),
                (__attribute__((address_space(3))) void*)(dst + (j * 512 + tid) * 8), 16, 0, 0);
    };

    f32x4 acc[4][4];
    #pragma unroll
    for (int i = 0; i < 4; ++i)
        #pragma unroll
        for (int j = 0; j < 4; ++j) acc[i][j] = (f32x4){0.f, 0.f, 0.f, 0.f};

    // prologue: stage steps 0 and 1 (12 loads); wait for step 0's 6
    stageW(0); stageX(0, 0); stageX(0, 2);
    stageW(1); stageX(1, 0); stageX(1, 2);
    asm volatile("s_waitcnt vmcnt(6)" ::: "memory");
    __builtin_amdgcn_sched_barrier(0);
    __builtin_amdgcn_s_barrier();

    #pragma unroll
    for (int t = 0; t < 18; ++t) {
        const __hip_bfloat16* Wb = &Wl[(t % 3) * 8192];
        const __hip_bfloat16* Xr = &Xl[(t % 3) * 16384];
        bool pre = (t + 2 < 18);
        bf16x8 b0, b1, b2, b3, a0, a1;

        // ---- phase 0: kh2=0, mi 0/1; stage W(t+2)
        b0 = *(const bf16x8*)&Xr[offB[0][0]];
        b1 = *(const bf16x8*)&Xr[offB[1][0]];
        b2 = *(const bf16x8*)&Xr[offB[2][0]];
        b3 = *(const bf16x8*)&Xr[offB[3][0]];
        a0 = *(const bf16x8*)&Wb[offA[0][0]];
        a1 = *(const bf16x8*)&Wb[offA[1][0]];
        if (pre) stageW(t + 2);
        __builtin_amdgcn_s_barrier();
        asm volatile("s_waitcnt lgkmcnt(0)" ::: "memory");
        __builtin_amdgcn_sched_barrier(0);
        __builtin_amdgcn_s_setprio(1);
        acc[0][0] = __builtin_amdgcn_mfma_f32_16x16x32_bf16(a0, b0, acc[0][0], 0, 0, 0);
        acc[0][1] = __builtin_amdgcn_mfma_f32_16x16x32_bf16(a0, b1, acc[0][1], 0, 0, 0);
        acc[0][2] = __builtin_amdgcn_mfma_f32_16x16x32_bf16(a0, b2, acc[0][2], 0, 0, 0);
        acc[0][3] = __builtin_amdgcn_mfma_f32_16x16x32_bf16(a0, b3, acc[0][3], 0, 0, 0);
        acc[1][0] = __builtin_amdgcn_mfma_f32_16x16x32_bf16(a1, b0, acc[1][0], 0, 0, 0);
        acc[1][1] = __builtin_amdgcn_mfma_f32_16x16x32_bf16(a1, b1, acc[1][1], 0, 0, 0);
        acc[1][2] = __builtin_amdgcn_mfma_f32_16x16x32_bf16(a1, b2, acc[1][2], 0, 0, 0);
        acc[1][3] = __builtin_amdgcn_mfma_f32_16x16x32_bf16(a1, b3, acc[1][3], 0, 0, 0);
        __builtin_amdgcn_s_setprio(0);
        __builtin_amdgcn_s_barrier();

        // ---- phase 1: kh2=0, mi 2/3 (reuse b frags); stage X(t+2) j0,j1
        a0 = *(const bf16x8*)&Wb[offA[2][0]];
        a1 = *(const bf16x8*)&Wb[offA[3][0]];
        if (pre) stageX(t + 2, 0);
        __builtin_amdgcn_s_barrier();
        asm volatile("s_waitcnt lgkmcnt(0)" ::: "memory");
        __builtin_amdgcn_sched_barrier(0);
        __builtin_amdgcn_s_setprio(1);
        acc[2][0] = __builtin_amdgcn_mfma_f32_16x16x32_bf16(a0, b0, acc[2][0], 0, 0, 0);
        acc[2][1] = __builtin_amdgcn_mfma_f32_16x16x32_bf16(a0, b1, acc[2][1], 0, 0, 0);
        acc[2][2] = __builtin_amdgcn_mfma_f32_16x16x32_bf16(a0, b2, acc[2][2], 0, 0, 0);
        acc[2][3] = __builtin_amdgcn_mfma_f32_16x16x32_bf16(a0, b3, acc[2][3], 0, 0, 0);
        acc[3][0] = __builtin_amdgcn_mfma_f32_16x16x32_bf16(a1, b0, acc[3][0], 0, 0, 0);
        acc[3][1] = __builtin_amdgcn_mfma_f32_16x16x32_bf16(a1, b1, acc[3][1], 0, 0, 0);
        acc[3][2] = __builtin_amdgcn_mfma_f32_16x16x32_bf16(a1, b2, acc[3][2], 0, 0, 0);
        acc[3][3] = __builtin_amdgcn_mfma_f32_16x16x32_bf16(a1, b3, acc[3][3], 0, 0, 0);
        __builtin_amdgcn_s_setprio(0);
        __builtin_amdgcn_s_barrier();

        // ---- phase 2: kh2=1, mi 0/1; stage X(t+2) j2,j3
        b0 = *(const bf16x8*)&Xr[offB[0][1]];
        b1 = *(const bf16x8*)&Xr[offB[1][1]];
        b2 = *(const bf16x8*)&Xr[offB[2][1]];
        b3 = *(const bf16x8*)&Xr[offB[3][1]];
        a0 = *(const bf16x8*)&Wb[offA[0][1]];
        a1 = *(const bf16x8*)&Wb[offA[1][1]];
        if (pre) stageX(t + 2, 2);
        __builtin_amdgcn_s_barrier();
        asm volatile("s_waitcnt lgkmcnt(0)" ::: "memory");
        __builtin_amdgcn_sched_barrier(0);
        __builtin_amdgcn_s_setprio(1);
        acc[0][0] = __builtin_amdgcn_mfma_f32_16x16x32_bf16(a0, b0, acc[0][0], 0, 0, 0);
        acc[0][1] = __builtin_amdgcn_mfma_f32_16x16x32_bf16(a0, b1, acc[0][1], 0, 0, 0);
        acc[0][2] = __builtin_amdgcn_mfma_f32_16x16x32_bf16(a0, b2, acc[0][2], 0, 0, 0);
        acc[0][3] = __builtin_amdgcn_mfma_f32_16x16x32_bf16(a0, b3, acc[0][3], 0, 0, 0);
        acc[1][0] = __builtin_amdgcn_mfma_f32_16x16x32_bf16(a1, b0, acc[1][0], 0, 0, 0);
        acc[1][1] = __builtin_amdgcn_mfma_f32_16x16x32_bf16(a1, b1, acc[1][1], 0, 0, 0);
        acc[1][2] = __builtin_amdgcn_mfma_f32_16x16x32_bf16(a1, b2, acc[1][2], 0, 0, 0);
        acc[1][3] = __builtin_amdgcn_mfma_f32_16x16x32_bf16(a1, b3, acc[1][3], 0, 0, 0);
        __builtin_amdgcn_s_setprio(0);
        __builtin_amdgcn_s_barrier();

        // ---- phase 3: kh2=1, mi 2/3; no staging
        a0 = *(const bf16x8*)&Wb[offA[2][1]];
        a1 = *(const bf16x8*)&Wb[offA[3][1]];
        __builtin_amdgcn_s_barrier();
        asm volatile("s_waitcnt lgkmcnt(0)" ::: "memory");
        __builtin_amdgcn_sched_barrier(0);
        __builtin_amdgcn_s_setprio(1);
        acc[2][0] = __builtin_amdgcn_mfma_f32_16x16x32_bf16(a0, b0, acc[2][0], 0, 0, 0);
        acc[2][1] = __builtin_amdgcn_mfma_f32_16x16x32_bf16(a0, b1, acc[2][1], 0, 0, 0);
        acc[2][2] = __builtin_amdgcn_mfma_f32_16x16x32_bf16(a0, b2, acc[2][2], 0, 0, 0);
        acc[2][3] = __builtin_amdgcn_mfma_f32_16x16x32_bf16(a0, b3, acc[2][3], 0, 0, 0);
        acc[3][0] = __builtin_amdgcn_mfma_f32_16x16x32_bf16(a1, b0, acc[3][0], 0, 0, 0);
        acc[3][1] = __builtin_amdgcn_mfma_f32_16x16x32_bf16(a1, b1, acc[3][1], 0, 0, 0);
        acc[3][2] = __builtin_amdgcn_mfma_f32_16x16x32_bf16(a1, b2, acc[3][2], 0, 0, 0);
        acc[3][3] = __builtin_amdgcn_mfma_f32_16x16x32_bf16(a1, b3, acc[3][3], 0, 0, 0);
        __builtin_amdgcn_s_setprio(0);

        // ---- step boundary: counted vmcnt, then barrier
        if (t < 16) {
            asm volatile("s_waitcnt vmcnt(6)" ::: "memory");
        } else if (t == 16) {
            asm volatile("s_waitcnt vmcnt(0)" ::: "memory");
        }
        __builtin_amdgcn_sched_barrier(0);
        if (t < 17) __builtin_amdgcn_s_barrier();
    }

    // fused bias + BN + SiLU epilogue
    #pragma unroll
    for (int mi = 0; mi < 4; ++mi) {
        #pragma unroll
        for (int r = 0; r < 4; ++r) {
            int o = wm * 64 + mi * 16 + u * 4 + r;
            float al = ab[o], be = ab[128 + o];
            size_t obase = (((size_t)n * 128 + o) * 128 + h0) * 128;
            #pragma unroll
            for (int ni = 0; ni < 4; ++ni) {
                int p = wn * 64 + ni * 16 + r16;
                int r2 = p >> 7, w = p & 127;
                float z = acc[mi][ni][r] * al + be;
                out[obase + r2 * 128 + w] = z / (1.f + __expf(-z));
            }
        }
    }
}

// ----------------------------------------------------------------- launch ---
extern "C" void kernel_launch(void* const* d_in, const int* in_sizes, int n_in,
                              void* d_out, int out_size, void* d_ws, size_t ws_size,
                              hipStream_t stream) {
    const float* x   = (const float*)d_in[0];
    const float* w1  = (const float*)d_in[1];
    const float* b1  = (const float*)d_in[2];
    const float* g1  = (const float*)d_in[3];
    const float* be1 = (const float*)d_in[4];
    const float* m1  = (const float*)d_in[5];
    const float* v1  = (const float*)d_in[6];
    const float* wh  = (const float*)d_in[7];
    const float* bh  = (const float*)d_in[8];
    const float* ww  = (const float*)d_in[9];
    const float* bw  = (const float*)d_in[10];
    const float* wc  = (const float*)d_in[11];
    const float* bc  = (const float*)d_in[12];
    const float* g2  = (const float*)d_in[13];
    const float* be2 = (const float*)d_in[14];
    const float* m2  = (const float*)d_in[15];
    const float* v2  = (const float*)d_in[16];
    float* out = (float*)d_out;

    char* ws = (char*)d_ws;
    float* P  = (float*)(ws);                                   // 1 MiB
    float* A2 = (float*)(ws + (1 << 20));                       // 1 MiB
    __hip_bfloat16* Xpad = (__hip_bfloat16*)(ws + (2 << 20));   // 34,611,200 B
    __hip_bfloat16* Wt   = (__hip_bfloat16*)(ws + (2 << 20) + 34611200);  // 294,912 B
    float* ab = (float*)(ws + (2 << 20) + 34611200 + 294912);   // 1 KiB

    pool_kernel<<<1024, 256, 0, stream>>>(x, P);
    attn_kernel<<<8, 256, 0, stream>>>(P, w1, b1, g1, be1, m1, v1, wh, bh, ww, bw, A2);
    wtrans_kernel<<<576, 256, 0, stream>>>(wc, bc, g2, be2, m2, v2, Wt, ab);
    border_kernel<<<258, 256, 0, stream>>>(Xpad);
    amul_kernel<<<1024, 256, 0, stream>>>(x, A2, Xpad);
    conv_kernel<<<512, 512, 0, stream>>>(Xpad, Wt, ab, out);
}

// Round 3
// 125.554 us; speedup vs baseline: 1.1251x; 1.0068x over previous
//
#include <hip/hip_runtime.h>
#include <hip/hip_bf16.h>

typedef float f32x4 __attribute__((ext_vector_type(4)));
typedef __bf16 bf16x8 __attribute__((ext_vector_type(8)));

#define EPSF 1e-5f

// ---------------------------------------------------------------- pooling ---
__device__ __forceinline__ float pw(int i) {
    return (1.0f + (i < 64 ? 2.0f : 0.0f) + (i < 32 ? 4.0f : 0.0f)) * (1.0f / 128.0f);
}

__global__ __launch_bounds__(256) void pool_kernel(const float* __restrict__ x,
                                                   float* __restrict__ P) {
    int nc = blockIdx.x;  // n*128 + c
    const f32x4* plane = (const f32x4*)(x + (size_t)nc * 16384);
    __shared__ float rowpart[128][33];
    __shared__ __align__(16) f32x4 colpart[8][32];
    int t = threadIdx.x;
    int wq = t & 31, hg = t >> 5;
    f32x4 cacc = {0.f, 0.f, 0.f, 0.f};
    float u0 = pw(wq * 4), u1 = pw(wq * 4 + 1), u2 = pw(wq * 4 + 2), u3 = pw(wq * 4 + 3);
    #pragma unroll
    for (int j = 0; j < 16; ++j) {
        int r = hg * 16 + j;
        f32x4 v = plane[r * 32 + wq];
        rowpart[r][wq] = v.x * u0 + v.y * u1 + v.z * u2 + v.w * u3;
        cacc += v * pw(r);
    }
    colpart[hg][wq] = cacc;
    __syncthreads();
    float s = 0.f;
    if (t < 128) {
        #pragma unroll
        for (int q = 0; q < 32; ++q) s += rowpart[t][q];
        P[(size_t)nc * 256 + t] = s;
    } else {
        int w = t - 128;
        const float* cp = (const float*)colpart;
        #pragma unroll
        for (int g = 0; g < 8; ++g) s += cp[g * 128 + w];
        P[(size_t)nc * 256 + 128 + w] = s;
    }
}

// ---------------------------------------------------- attention vectors -----
__global__ __launch_bounds__(256) void attn_kernel(const float* __restrict__ P,
    const float* __restrict__ w1, const float* __restrict__ b1,
    const float* __restrict__ g1, const float* __restrict__ be1,
    const float* __restrict__ m1, const float* __restrict__ v1,
    const float* __restrict__ wh, const float* __restrict__ bh,
    const float* __restrict__ ww, const float* __restrict__ bw,
    float* __restrict__ A2) {
    int n = blockIdx.x, t = threadIdx.x;
    __shared__ float w1s[1024], whs[1024], wws[1024];
    __shared__ float bhs[128], bws[128];
    __shared__ float s1[8], t1[8], b1s[8];
    for (int i = t; i < 1024; i += 256) { w1s[i] = w1[i]; whs[i] = wh[i]; wws[i] = ww[i]; }
    if (t < 128) { bhs[t] = bh[t]; bws[t] = bw[t]; }
    if (t < 8) {
        float s = g1[t] * rsqrtf(v1[t] + EPSF);
        s1[t] = s; t1[t] = be1[t] - m1[t] * s; b1s[t] = b1[t];
    }
    __syncthreads();
    float y[8];
    #pragma unroll
    for (int m = 0; m < 8; ++m) y[m] = b1s[m];
    const float* Pn = P + (size_t)n * 32768;
    for (int c = 0; c < 128; ++c) {
        float pv = Pn[c * 256 + t];
        #pragma unroll
        for (int m = 0; m < 8; ++m) y[m] += w1s[m * 128 + c] * pv;
    }
    #pragma unroll
    for (int m = 0; m < 8; ++m) {
        float v = y[m] * s1[m] + t1[m];
        float cl = fminf(fmaxf(v + 3.f, 0.f), 6.f);
        y[m] = v * cl * (1.f / 6.f);
    }
    const float* Ws = (t < 128) ? whs : wws;   // wave-uniform
    const float* Bs = (t < 128) ? bhs : bws;
    float* On = A2 + (size_t)n * 32768;
    for (int c = 0; c < 128; ++c) {
        float a = Bs[c];
        #pragma unroll
        for (int m = 0; m < 8; ++m) a += y[m] * Ws[c * 8 + m];
        On[c * 256 + t] = 1.f / (1.f + __expf(-a));
    }
}

// -------------------------------------------- weight transform + BN consts --
__global__ __launch_bounds__(256) void wtrans_kernel(const float* __restrict__ wc,
    const float* __restrict__ bc, const float* __restrict__ g2, const float* __restrict__ be2,
    const float* __restrict__ m2, const float* __restrict__ v2,
    __hip_bfloat16* __restrict__ Wt, float* __restrict__ ab) {
    int g = blockIdx.x * 256 + threadIdx.x;   // 576*256 == 147456 exactly
    int khw = g >> 14, rem = g & 16383, o = rem >> 7, c = rem & 127;
    Wt[g] = __float2bfloat16(wc[(o * 128 + c) * 9 + khw]);
    if (g < 128) {
        float s2 = g2[g] * rsqrtf(v2[g] + EPSF);
        ab[g] = s2;
        ab[128 + g] = bc[g] * s2 + be2[g] - m2[g] * s2;
    }
}

// ------------------------------------------------------------ zero borders --
__global__ __launch_bounds__(256) void border_kernel(__hip_bfloat16* __restrict__ Xpad) {
    int g = blockIdx.x * 256 + threadIdx.x;   // 66048 uint4 writes
    if (g >= 66048) return;
    int pi = g >> 4, cb = g & 15;
    int n = pi / 516, b = pi - n * 516;
    int hp, wp;
    if (b < 130)      { hp = 0;   wp = b; }
    else if (b < 260) { hp = 129; wp = b - 130; }
    else if (b < 388) { wp = 0;   hp = b - 259; }
    else              { wp = 129; hp = b - 387; }
    uint4 z = {0u, 0u, 0u, 0u};
    *(uint4*)(Xpad + (size_t)(n * 16900 + hp * 130 + wp) * 128 + cb * 8) = z;
}

// ------------------------------------------- attention multiply -> NHWC bf16
__device__ __forceinline__ int ldsoff(int w, int c) {
    return w * 128 + ((((c >> 3) ^ ((w & 7) << 1)) << 3) | (c & 7));
}

__global__ __launch_bounds__(256) void amul_kernel(const float* __restrict__ x,
    const float* __restrict__ A2, __hip_bfloat16* __restrict__ Xpad) {
    int nh = blockIdx.x;             // n*128 + h
    int n = nh >> 7, h = nh & 127;
    int t = threadIdx.x;
    __shared__ __align__(16) __hip_bfloat16 T[16384];
    __shared__ float ahs[128];
    if (t < 128) ahs[t] = A2[(size_t)(n * 128 + t) * 256 + h];
    __syncthreads();
    const float* xr  = x + ((size_t)n * 128 * 128 + h) * 128;
    const float* awr = A2 + (size_t)n * 32768 + 128;
    #pragma unroll
    for (int j = 0; j < 16; ++j) {
        int item = j * 256 + t;
        int c = item >> 5, w4 = item & 31;
        f32x4 xv = *(const f32x4*)(xr + (size_t)c * 16384 + w4 * 4);
        f32x4 av = *(const f32x4*)(awr + c * 256 + w4 * 4);
        float ah = ahs[c];
        #pragma unroll
        for (int k = 0; k < 4; ++k) {
            float val = xv[k] * av[k] * ah;
            T[ldsoff(w4 * 4 + k, c)] = __float2bfloat16(val);
        }
    }
    __syncthreads();
    __hip_bfloat16* orow = Xpad + (size_t)(n * 16900 + (h + 1) * 130 + 1) * 128;
    #pragma unroll
    for (int j = 0; j < 8; ++j) {
        int item = j * 256 + t;
        int w = item >> 4, cb = item & 15;
        int slot = cb ^ ((w & 7) << 1);
        uint4 v = *(const uint4*)&T[w * 128 + slot * 8];
        *(uint4*)(orow + w * 128 + cb * 8) = v;
    }
}

// ------------------------------------------------------- implicit-GEMM conv -
// 512 threads (8 waves, 2Mx4N), tile M=128 (outch) x N=256 (2 output rows),
// BK=64, triple-buffered LDS, ONE barrier per K-step, counted vmcnt.
// Per step: stage(t+2) || 8 ds_read(k2=0); lgkm; 16 MFMA; 8 ds_read(k2=1);
//           lgkm; 16 MFMA; vmcnt(6); s_barrier.
__global__ __launch_bounds__(512, 2) void conv_kernel(
    const __hip_bfloat16* __restrict__ Xpad, const __hip_bfloat16* __restrict__ Wt,
    const float* __restrict__ ab, float* __restrict__ out) {
    int bid = blockIdx.x;
    int work = (bid & 7) * 64 + (bid >> 3);   // XCD swizzle, 512 % 8 == 0
    int n = work >> 6, h0 = (work & 63) * 2;
    int tid = threadIdx.x;
    int lane = tid & 63, wid = tid >> 6;
    int wm = wid >> 2, wn = wid & 3;
    int r16 = lane & 15, u = lane >> 4;

    __shared__ __hip_bfloat16 Wl[3 * 8192];    // [buf][o=128][k=64]
    __shared__ __hip_bfloat16 Xl[3 * 16384];   // [buf][p=256][k=64]

    const __hip_bfloat16* Xb = Xpad + (size_t)n * (16900 * 128) + h0 * 130 * 128;

    // per-thread staging source offsets (elements), swizzle-inverted on source
    int woff[2], xoff[4];
    #pragma unroll
    for (int j = 0; j < 2; ++j) {
        int idx = j * 512 + tid, o = idx >> 3, s = idx & 7;
        woff[j] = o * 128 + ((s ^ (o & 7)) << 3);
    }
    #pragma unroll
    for (int j = 0; j < 4; ++j) {
        int idx = j * 512 + tid, r = idx >> 3, s = idx & 7;
        int r2 = r >> 7, w = r & 127;
        xoff[j] = (r2 * 130 + w) * 128 + ((s ^ (r & 7)) << 3);
    }
    // fragment ds_read offsets (swizzled)
    int swz[2];
    swz[0] = ((0 + u) ^ (r16 & 7)) << 3;
    swz[1] = ((4 + u) ^ (r16 & 7)) << 3;
    int offA[4][2], offB[4][2];
    #pragma unroll
    for (int i = 0; i < 4; ++i) {
        int o = wm * 64 + i * 16 + r16;
        int p = wn * 64 + i * 16 + r16;
        #pragma unroll
        for (int k2 = 0; k2 < 2; ++k2) {
            offA[i][k2] = o * 64 + swz[k2];
            offB[i][k2] = p * 64 + swz[k2];
        }
    }

    auto stageW = [&](int t) {
        int khw = t >> 1, ch = t & 1;
        const __hip_bfloat16* src = Wt + khw * 16384 + ch * 64;
        __hip_bfloat16* dst = &Wl[(t % 3) * 8192];
        #pragma unroll
        for (int j = 0; j < 2; ++j)
            __builtin_amdgcn_global_load_lds(
                (const __attribute__((address_space(1))) void*)(src + woff[j]),
                (__attribute__((address_space(3))) void*)(dst + (j * 512 + tid) * 8), 16, 0, 0);
    };
    auto stageX = [&](int t) {
        int khw = t >> 1, ch = t & 1;
        int kh = (khw * 11) >> 5, kw = khw - kh * 3;
        const __hip_bfloat16* src = Xb + (kh * 130 + kw) * 128 + ch * 64;
        __hip_bfloat16* dst = &Xl[(t % 3) * 16384];
        #pragma unroll
        for (int j = 0; j < 4; ++j)
            __builtin_amdgcn_global_load_lds(
                (const __attribute__((address_space(1))) void*)(src + xoff[j]),
                (__attribute__((address_space(3))) void*)(dst + (j * 512 + tid) * 8), 16, 0, 0);
    };

    f32x4 acc[4][4];
    #pragma unroll
    for (int i = 0; i < 4; ++i)
        #pragma unroll
        for (int j = 0; j < 4; ++j) acc[i][j] = (f32x4){0.f, 0.f, 0.f, 0.f};

    // prologue: stage steps 0 and 1 (12 loads); wait for step 0's 6
    stageW(0); stageX(0);
    stageW(1); stageX(1);
    asm volatile("s_waitcnt vmcnt(6)" ::: "memory");
    __builtin_amdgcn_sched_barrier(0);
    __builtin_amdgcn_s_barrier();
    __builtin_amdgcn_sched_barrier(0);

    #pragma unroll
    for (int t = 0; t < 18; ++t) {
        const __hip_bfloat16* Wb = &Wl[(t % 3) * 8192];
        const __hip_bfloat16* Xr = &Xl[(t % 3) * 16384];

        // issue next-next staging first (deadline is 2 steps out)
        if (t + 2 < 18) { stageW(t + 2); stageX(t + 2); }

        // ---- phase 0: k2=0 frags
        bf16x8 a0 = *(const bf16x8*)&Wb[offA[0][0]];
        bf16x8 a1 = *(const bf16x8*)&Wb[offA[1][0]];
        bf16x8 a2 = *(const bf16x8*)&Wb[offA[2][0]];
        bf16x8 a3 = *(const bf16x8*)&Wb[offA[3][0]];
        bf16x8 b0 = *(const bf16x8*)&Xr[offB[0][0]];
        bf16x8 b1 = *(const bf16x8*)&Xr[offB[1][0]];
        bf16x8 b2 = *(const bf16x8*)&Xr[offB[2][0]];
        bf16x8 b3 = *(const bf16x8*)&Xr[offB[3][0]];
        asm volatile("s_waitcnt lgkmcnt(0)" ::: "memory");
        __builtin_amdgcn_sched_barrier(0);
        __builtin_amdgcn_s_setprio(1);
        acc[0][0] = __builtin_amdgcn_mfma_f32_16x16x32_bf16(a0, b0, acc[0][0], 0, 0, 0);
        acc[0][1] = __builtin_amdgcn_mfma_f32_16x16x32_bf16(a0, b1, acc[0][1], 0, 0, 0);
        acc[0][2] = __builtin_amdgcn_mfma_f32_16x16x32_bf16(a0, b2, acc[0][2], 0, 0, 0);
        acc[0][3] = __builtin_amdgcn_mfma_f32_16x16x32_bf16(a0, b3, acc[0][3], 0, 0, 0);
        acc[1][0] = __builtin_amdgcn_mfma_f32_16x16x32_bf16(a1, b0, acc[1][0], 0, 0, 0);
        acc[1][1] = __builtin_amdgcn_mfma_f32_16x16x32_bf16(a1, b1, acc[1][1], 0, 0, 0);
        acc[1][2] = __builtin_amdgcn_mfma_f32_16x16x32_bf16(a1, b2, acc[1][2], 0, 0, 0);
        acc[1][3] = __builtin_amdgcn_mfma_f32_16x16x32_bf16(a1, b3, acc[1][3], 0, 0, 0);
        acc[2][0] = __builtin_amdgcn_mfma_f32_16x16x32_bf16(a2, b0, acc[2][0], 0, 0, 0);
        acc[2][1] = __builtin_amdgcn_mfma_f32_16x16x32_bf16(a2, b1, acc[2][1], 0, 0, 0);
        acc[2][2] = __builtin_amdgcn_mfma_f32_16x16x32_bf16(a2, b2, acc[2][2], 0, 0, 0);
        acc[2][3] = __builtin_amdgcn_mfma_f32_16x16x32_bf16(a2, b3, acc[2][3], 0, 0, 0);
        acc[3][0] = __builtin_amdgcn_mfma_f32_16x16x32_bf16(a3, b0, acc[3][0], 0, 0, 0);
        acc[3][1] = __builtin_amdgcn_mfma_f32_16x16x32_bf16(a3, b1, acc[3][1], 0, 0, 0);
        acc[3][2] = __builtin_amdgcn_mfma_f32_16x16x32_bf16(a3, b2, acc[3][2], 0, 0, 0);
        acc[3][3] = __builtin_amdgcn_mfma_f32_16x16x32_bf16(a3, b3, acc[3][3], 0, 0, 0);
        __builtin_amdgcn_s_setprio(0);

        // ---- phase 1: k2=1 frags (separate regs; may co-schedule with phase-0 MFMAs)
        bf16x8 c0 = *(const bf16x8*)&Wb[offA[0][1]];
        bf16x8 c1 = *(const bf16x8*)&Wb[offA[1][1]];
        bf16x8 c2 = *(const bf16x8*)&Wb[offA[2][1]];
        bf16x8 c3 = *(const bf16x8*)&Wb[offA[3][1]];
        bf16x8 d0 = *(const bf16x8*)&Xr[offB[0][1]];
        bf16x8 d1 = *(const bf16x8*)&Xr[offB[1][1]];
        bf16x8 d2 = *(const bf16x8*)&Xr[offB[2][1]];
        bf16x8 d3 = *(const bf16x8*)&Xr[offB[3][1]];
        asm volatile("s_waitcnt lgkmcnt(0)" ::: "memory");
        __builtin_amdgcn_sched_barrier(0);
        __builtin_amdgcn_s_setprio(1);
        acc[0][0] = __builtin_amdgcn_mfma_f32_16x16x32_bf16(c0, d0, acc[0][0], 0, 0, 0);
        acc[0][1] = __builtin_amdgcn_mfma_f32_16x16x32_bf16(c0, d1, acc[0][1], 0, 0, 0);
        acc[0][2] = __builtin_amdgcn_mfma_f32_16x16x32_bf16(c0, d2, acc[0][2], 0, 0, 0);
        acc[0][3] = __builtin_amdgcn_mfma_f32_16x16x32_bf16(c0, d3, acc[0][3], 0, 0, 0);
        acc[1][0] = __builtin_amdgcn_mfma_f32_16x16x32_bf16(c1, d0, acc[1][0], 0, 0, 0);
        acc[1][1] = __builtin_amdgcn_mfma_f32_16x16x32_bf16(c1, d1, acc[1][1], 0, 0, 0);
        acc[1][2] = __builtin_amdgcn_mfma_f32_16x16x32_bf16(c1, d2, acc[1][2], 0, 0, 0);
        acc[1][3] = __builtin_amdgcn_mfma_f32_16x16x32_bf16(c1, d3, acc[1][3], 0, 0, 0);
        acc[2][0] = __builtin_amdgcn_mfma_f32_16x16x32_bf16(c2, d0, acc[2][0], 0, 0, 0);
        acc[2][1] = __builtin_amdgcn_mfma_f32_16x16x32_bf16(c2, d1, acc[2][1], 0, 0, 0);
        acc[2][2] = __builtin_amdgcn_mfma_f32_16x16x32_bf16(c2, d2, acc[2][2], 0, 0, 0);
        acc[2][3] = __builtin_amdgcn_mfma_f32_16x16x32_bf16(c2, d3, acc[2][3], 0, 0, 0);
        acc[3][0] = __builtin_amdgcn_mfma_f32_16x16x32_bf16(c3, d0, acc[3][0], 0, 0, 0);
        acc[3][1] = __builtin_amdgcn_mfma_f32_16x16x32_bf16(c3, d1, acc[3][1], 0, 0, 0);
        acc[3][2] = __builtin_amdgcn_mfma_f32_16x16x32_bf16(c3, d2, acc[3][2], 0, 0, 0);
        acc[3][3] = __builtin_amdgcn_mfma_f32_16x16x32_bf16(c3, d3, acc[3][3], 0, 0, 0);
        __builtin_amdgcn_s_setprio(0);

        // ---- step boundary: counted vmcnt, ONE barrier
        if (t < 16) {
            asm volatile("s_waitcnt vmcnt(6)" ::: "memory");
        } else if (t == 16) {
            asm volatile("s_waitcnt vmcnt(0)" ::: "memory");
        }
        __builtin_amdgcn_sched_barrier(0);
        if (t < 17) {
            __builtin_amdgcn_s_barrier();
            __builtin_amdgcn_sched_barrier(0);
        }
    }

    // fused bias + BN + SiLU epilogue
    #pragma unroll
    for (int mi = 0; mi < 4; ++mi) {
        #pragma unroll
        for (int r = 0; r < 4; ++r) {
            int o = wm * 64 + mi * 16 + u * 4 + r;
            float al = ab[o], be = ab[128 + o];
            size_t obase = (((size_t)n * 128 + o) * 128 + h0) * 128;
            #pragma unroll
            for (int ni = 0; ni < 4; ++ni) {
                int p = wn * 64 + ni * 16 + r16;
                int r2 = p >> 7, w = p & 127;
                float z = acc[mi][ni][r] * al + be;
                out[obase + r2 * 128 + w] = z / (1.f + __expf(-z));
            }
        }
    }
}

// ----------------------------------------------------------------- launch ---
extern "C" void kernel_launch(void* const* d_in, const int* in_sizes, int n_in,
                              void* d_out, int out_size, void* d_ws, size_t ws_size,
                              hipStream_t stream) {
    const float* x   = (const float*)d_in[0];
    const float* w1  = (const float*)d_in[1];
    const float* b1  = (const float*)d_in[2];
    const float* g1  = (const float*)d_in[3];
    const float* be1 = (const float*)d_in[4];
    const float* m1  = (const float*)d_in[5];
    const float* v1  = (const float*)d_in[6];
    const float* wh  = (const float*)d_in[7];
    const float* bh  = (const float*)d_in[8];
    const float* ww  = (const float*)d_in[9];
    const float* bw  = (const float*)d_in[10];
    const float* wc  = (const float*)d_in[11];
    const float* bc  = (const float*)d_in[12];
    const float* g2  = (const float*)d_in[13];
    const float* be2 = (const float*)d_in[14];
    const float* m2  = (const float*)d_in[15];
    const float* v2  = (const float*)d_in[16];
    float* out = (float*)d_out;

    char* ws = (char*)d_ws;
    float* P  = (float*)(ws);                                   // 1 MiB
    float* A2 = (float*)(ws + (1 << 20));                       // 1 MiB
    __hip_bfloat16* Xpad = (__hip_bfloat16*)(ws + (2 << 20));   // 34,611,200 B
    __hip_bfloat16* Wt   = (__hip_bfloat16*)(ws + (2 << 20) + 34611200);  // 294,912 B
    float* ab = (float*)(ws + (2 << 20) + 34611200 + 294912);   // 1 KiB

    pool_kernel<<<1024, 256, 0, stream>>>(x, P);
    attn_kernel<<<8, 256, 0, stream>>>(P, w1, b1, g1, be1, m1, v1, wh, bh, ww, bw, A2);
    wtrans_kernel<<<576, 256, 0, stream>>>(wc, bc, g2, be2, m2, v2, Wt, ab);
    border_kernel<<<258, 256, 0, stream>>>(Xpad);
    amul_kernel<<<1024, 256, 0, stream>>>(x, A2, Xpad);
    conv_kernel<<<512, 512, 0, stream>>>(Xpad, Wt, ab, out);
}